// Round 2
// 188.918 us; speedup vs baseline: 1.0635x; 1.0635x over previous
//
#include <hip/hip_runtime.h>
#include <cmath>

#define NN    4096
#define FIN   32
#define KSEL  39      // neighbors kept (top-40 minus self)
#define PP    22
#define PPAD  24
#define FOUT  48
#define WPB   2       // waves per block
#define QW    4       // queries per wave
#define CAP   128     // candidate cap per query (fallback if exceeded)
#define WCOLS 32      // combined weight columns: [Wf(22) | pad(2) | Ws(4) | pad(4)]

#define WSYNC() asm volatile("s_waitcnt lgkmcnt(0)" ::: "memory")

__device__ __forceinline__ int lane_prefix(unsigned long long m) {
    return __builtin_amdgcn_mbcnt_hi((unsigned)(m >> 32),
           __builtin_amdgcn_mbcnt_lo((unsigned)m, 0));
}

// ---------------- precompute: 4 threads per point, LDS-staged weights ------------
// Combined col map: c<22 -> Wf col c ; 24<=c<28 -> Ws col (c-24) ; else 0.
// h=0: feat cols 0..7, h=1: 8..15, h=2: 16..23 (incl. zero pads 22,23),
// h=3: cols 24..27 = coords (+ |c|^2), cols 28..31 dummy.
__global__ __launch_bounds__(256) void gn_pre(
    const float* __restrict__ x,
    const float* __restrict__ Wf, const float* __restrict__ bf,
    const float* __restrict__ Ws, const float* __restrict__ bs,
    float* __restrict__ coords4, float* __restrict__ feats,
    float* __restrict__ sqn)
{
    __shared__ __align__(16) float sW[FIN * WCOLS];
    __shared__ float sB[WCOLS];

    int t = threadIdx.x;
    for (int idx = t; idx < FIN * WCOLS; idx += 256) {
        int i = idx >> 5, c = idx & 31;
        float v = 0.f;
        if (c < PP) v = Wf[i * PP + c];
        else if (c >= 24 && c < 28) v = Ws[i * 4 + (c - 24)];
        sW[idx] = v;
    }
    if (t < WCOLS) {
        float v = 0.f;
        if (t < PP) v = bf[t];
        else if (t >= 24 && t < 28) v = bs[t - 24];
        sB[t] = v;
    }
    __syncthreads();

    int gid = blockIdx.x * 256 + t;
    int p = gid >> 2;          // point
    int h = gid & 3;           // column strip
    int c0 = h * 8;

    const float4* xr4 = (const float4*)(x + (size_t)p * FIN);
    float acc[8];
    #pragma unroll
    for (int k = 0; k < 8; ++k) acc[k] = sB[c0 + k];

    // accumulate over i ascending -- bit-identical order to reference kernel
    #pragma unroll
    for (int i = 0; i < 8; ++i) {
        float4 xt = xr4[i];
        const float* w0 = sW + (4 * i + 0) * WCOLS + c0;
        const float* w1 = sW + (4 * i + 1) * WCOLS + c0;
        const float* w2 = sW + (4 * i + 2) * WCOLS + c0;
        const float* w3 = sW + (4 * i + 3) * WCOLS + c0;
        #pragma unroll
        for (int k = 0; k < 8; ++k) acc[k] = fmaf(xt.x, w0[k], acc[k]);
        #pragma unroll
        for (int k = 0; k < 8; ++k) acc[k] = fmaf(xt.y, w1[k], acc[k]);
        #pragma unroll
        for (int k = 0; k < 8; ++k) acc[k] = fmaf(xt.z, w2[k], acc[k]);
        #pragma unroll
        for (int k = 0; k < 8; ++k) acc[k] = fmaf(xt.w, w3[k], acc[k]);
    }

    if (h < 3) {
        float4* fw = (float4*)(feats + (size_t)p * PPAD + c0);
        fw[0] = make_float4(acc[0], acc[1], acc[2], acc[3]);
        fw[1] = make_float4(acc[4], acc[5], acc[6], acc[7]);   // h=2: cols 22,23 are exact 0
    } else {
        ((float4*)coords4)[p] = make_float4(acc[0], acc[1], acc[2], acc[3]);
        sqn[p] = fmaf(acc[0], acc[0], fmaf(acc[1], acc[1],
                 fmaf(acc[2], acc[2], acc[3] * acc[3])));
    }
}

// ---- fallback-only helpers (degenerate C > CAP path) ----------------------------
__device__ __forceinline__ void sort64_pair(float& v, int& m, int lane) {
    #pragma unroll
    for (int k = 2; k <= 64; k <<= 1) {
        #pragma unroll
        for (int j = k >> 1; j >= 1; j >>= 1) {
            float ov = __shfl_xor(v, j);
            int   om = __shfl_xor(m, j);
            bool keepMin = (((lane & j) == 0) == ((lane & k) == 0));
            bool less = (ov < v) || (ov == v && om < m);
            bool take = (less == keepMin);
            v = take ? ov : v;
            m = take ? om : m;
        }
    }
}
__device__ __forceinline__ void merge64(float& Lv, int& Lm, float cv, int cm, int lane) {
    float rv = __shfl_xor(cv, 63);
    int   rm = __shfl_xor(cm, 63);
    bool less = (rv < Lv) || (rv == Lv && rm < Lm);
    if (less) { Lv = rv; Lm = rm; }
    #pragma unroll
    for (int j = 32; j >= 1; j >>= 1) {
        float ov = __shfl_xor(Lv, j);
        int   om = __shfl_xor(Lm, j);
        bool lower = ((lane & j) == 0);
        bool l2 = (ov < Lv) || (ov == Lv && om < Lm);
        bool take = (l2 == lower);
        Lv = take ? ov : Lv;
        Lm = take ? om : Lm;
    }
}

// ---------------- per-query tail: selection + stage + aggregate + epilogue -------
// ALL state is scalar. Called 4 times explicitly (no runtime-j loop, no arrays --
// runtime-indexed private arrays demote to scratch).
__device__ __forceinline__ void tail_query(
    int lane, int b, int nj, int qj, int C,
    const unsigned short* __restrict__ selq,
    const float4* __restrict__ c4, const float* __restrict__ sqb,
    const float* __restrict__ feats,
    const float* __restrict__ x, const float* __restrict__ Wo,
    const float* __restrict__ bo,
    float* __restrict__ fstage, float* __restrict__ agg,
    float* __restrict__ out)
{
    const float INF = __builtin_inff();
    const float NEGINF = -INF;
    float4 cqj = c4[nj];
    float sqnj = sqb[nj];

    if (C <= CAP) {
        unsigned kd0 = 0xFFFFFFFFu, ki0 = 0xFFFFFFFFu; float dv0 = 0.f;
        if (lane < C) {
            unsigned idx = (unsigned)selq[lane];
            float4 cm = c4[idx];
            float s2 = sqb[idx];
            float dt = fmaf(cqj.x, cm.x, fmaf(cqj.y, cm.y, fmaf(cqj.z, cm.z, cqj.w * cm.w)));
            float d  = fmaxf(fmaf(-2.f, dt, s2 + sqnj), 0.f);
            dv0 = d; kd0 = __float_as_uint(d); ki0 = idx;
        }
        unsigned kd1 = 0xFFFFFFFFu, ki1 = 0xFFFFFFFFu; float dv1 = 0.f;
        if (64 + lane < C) {
            unsigned idx = (unsigned)selq[64 + lane];
            float4 cm = c4[idx];
            float s2 = sqb[idx];
            float dt = fmaf(cqj.x, cm.x, fmaf(cqj.y, cm.y, fmaf(cqj.z, cm.z, cqj.w * cm.w)));
            float d  = fmaxf(fmaf(-2.f, dt, s2 + sqnj), 0.f);
            dv1 = d; kd1 = __float_as_uint(d); ki1 = idx;
        }
        // D = exact 39th-smallest clamped d2 bits (must stay exact)
        unsigned D = 0;
        for (int bit = 30; bit >= 0; --bit) {
            unsigned t = D | (1u << bit);
            int c = (int)__popcll(__ballot(kd0 < t))
                  + (int)__popcll(__ballot(kd1 < t));
            if (c < KSEL) D = t;
        }
        int cless  = (int)__popcll(__ballot(kd0 < D))
                   + (int)__popcll(__ballot(kd1 < D));
        int tiecnt = (int)__popcll(__ballot(kd0 == D))
                   + (int)__popcll(__ballot(kd1 == D));
        int tneed = KSEL - cless;
        unsigned TI = 0xFFFFFFFFu;
        if (tiecnt > tneed) {            // rare: resolve ties by lowest index
            unsigned pi = 0;
            for (int bit = 11; bit >= 0; --bit) {
                unsigned t = pi | (1u << bit);
                int c = (int)__popcll(__ballot((kd0 == D) && (ki0 < t)))
                      + (int)__popcll(__ballot((kd1 == D) && (ki1 < t)));
                if (c < tneed) pi = t;
            }
            TI = pi;
        }
        // stage the exactly-39 selected neighbors (ballot/prefix slots, no atomics)
        bool take0 = (kd0 < D) || ((kd0 == D) && (ki0 <= TI));
        bool take1 = (kd1 < D) || ((kd1 == D) && (ki1 <= TI));
        unsigned long long tb0 = __ballot(take0);
        unsigned long long tb1 = __ballot(take1);
        unsigned base1 = (unsigned)__popcll(tb0);
        if (take0) {
            unsigned slot = (unsigned)lane_prefix(tb0);
            float wgt = __expf(-10.f * dv0);
            const float4* fr = (const float4*)(feats + ((size_t)b * NN + ki0) * PPAD);
            float4 f0 = fr[0], f1 = fr[1], f2 = fr[2], f3 = fr[3], f4 = fr[4], f5 = fr[5];
            float4* row = (float4*)(fstage + slot * PPAD);
            row[0] = make_float4(f0.x * wgt, f0.y * wgt, f0.z * wgt, f0.w * wgt);
            row[1] = make_float4(f1.x * wgt, f1.y * wgt, f1.z * wgt, f1.w * wgt);
            row[2] = make_float4(f2.x * wgt, f2.y * wgt, f2.z * wgt, f2.w * wgt);
            row[3] = make_float4(f3.x * wgt, f3.y * wgt, f3.z * wgt, f3.w * wgt);
            row[4] = make_float4(f4.x * wgt, f4.y * wgt, f4.z * wgt, f4.w * wgt);
            row[5] = make_float4(f5.x * wgt, f5.y * wgt, f5.z * wgt, f5.w * wgt);
        }
        if (take1) {
            unsigned slot = base1 + (unsigned)lane_prefix(tb1);
            float wgt = __expf(-10.f * dv1);
            const float4* fr = (const float4*)(feats + ((size_t)b * NN + ki1) * PPAD);
            float4 f0 = fr[0], f1 = fr[1], f2 = fr[2], f3 = fr[3], f4 = fr[4], f5 = fr[5];
            float4* row = (float4*)(fstage + slot * PPAD);
            row[0] = make_float4(f0.x * wgt, f0.y * wgt, f0.z * wgt, f0.w * wgt);
            row[1] = make_float4(f1.x * wgt, f1.y * wgt, f1.z * wgt, f1.w * wgt);
            row[2] = make_float4(f2.x * wgt, f2.y * wgt, f2.z * wgt, f2.w * wgt);
            row[3] = make_float4(f3.x * wgt, f3.y * wgt, f3.z * wgt, f3.w * wgt);
            row[4] = make_float4(f4.x * wgt, f4.y * wgt, f4.z * wgt, f4.w * wgt);
            row[5] = make_float4(f5.x * wgt, f5.y * wgt, f5.z * wgt, f5.w * wgt);
        }
    } else {
        // degenerate fallback: exact streaming top-64 over all 4096
        float Lv = INF; int Lm = 0x7FFFFFFF;
        for (int c = 0; c < 64; ++c) {
            int m = c * 64 + lane;
            float4 cm = c4[m];
            float s2 = sqb[m];
            float dt = fmaf(cqj.x, cm.x, fmaf(cqj.y, cm.y, fmaf(cqj.z, cm.z, cqj.w * cm.w)));
            float v  = fmaxf(fmaf(-2.f, dt, s2 + sqnj), 0.f);
            if (m == nj) v = INF;
            sort64_pair(v, m, lane);
            if (c == 0) { Lv = v; Lm = m; }
            else        merge64(Lv, Lm, v, m, lane);
        }
        if (lane < KSEL) {
            float wgt = __expf(-10.f * Lv);
            const float4* fr = (const float4*)(feats + ((size_t)b * NN + Lm) * PPAD);
            float4 f0 = fr[0], f1 = fr[1], f2 = fr[2], f3 = fr[3], f4 = fr[4], f5 = fr[5];
            float4* row = (float4*)(fstage + lane * PPAD);
            row[0] = make_float4(f0.x * wgt, f0.y * wgt, f0.z * wgt, f0.w * wgt);
            row[1] = make_float4(f1.x * wgt, f1.y * wgt, f1.z * wgt, f1.w * wgt);
            row[2] = make_float4(f2.x * wgt, f2.y * wgt, f2.z * wgt, f2.w * wgt);
            row[3] = make_float4(f3.x * wgt, f3.y * wgt, f3.z * wgt, f3.w * wgt);
            row[4] = make_float4(f4.x * wgt, f4.y * wgt, f4.z * wgt, f4.w * wgt);
            row[5] = make_float4(f5.x * wgt, f5.y * wgt, f5.z * wgt, f5.w * wgt);
        }
    }
    WSYNC();

    // ---- max / mean over 39 neighbors: 44 lanes, split-k ----
    if (lane < 2 * PP) {
        int g  = (lane >= PP) ? 1 : 0;
        int c  = lane - g * PP;
        int k0 = g ? 20 : 0;
        int k1 = g ? KSEL : 20;
        float mx = NEGINF, sm = 0.f;
        for (int k = k0; k < k1; ++k) {
            float v = fstage[k * PPAD + c];
            mx = fmaxf(mx, v);
            sm += v;
        }
        float mx2 = __shfl(mx, lane + PP);
        float sm2 = __shfl(sm, lane + PP);
        if (lane < PP) {
            agg[c]      = fmaxf(mx, mx2);
            agg[PP + c] = (sm + sm2) * (1.f / (float)KSEL);
        }
    }
    WSYNC();

    // ---- epilogue: out = tanh([x | max | mean] @ Wo + bo), fast tanh ----
    // 4-way split accumulators to break the 76-deep serial FMA chain.
    if (lane < FOUT) {
        const float* xr  = x + (size_t)qj * FIN;
        const float* woL = Wo + lane;
        float a0 = bo[lane], a1 = 0.f, a2 = 0.f, a3 = 0.f;
        #pragma unroll
        for (int f = 0; f < FIN; f += 4) {
            a0 = fmaf(xr[f + 0], woL[(f + 0) * FOUT], a0);
            a1 = fmaf(xr[f + 1], woL[(f + 1) * FOUT], a1);
            a2 = fmaf(xr[f + 2], woL[(f + 2) * FOUT], a2);
            a3 = fmaf(xr[f + 3], woL[(f + 3) * FOUT], a3);
        }
        #pragma unroll
        for (int f = 0; f < 2 * PP; f += 4) {
            a0 = fmaf(agg[f + 0], woL[(FIN + f + 0) * FOUT], a0);
            a1 = fmaf(agg[f + 1], woL[(FIN + f + 1) * FOUT], a1);
            a2 = fmaf(agg[f + 2], woL[(FIN + f + 2) * FOUT], a2);
            a3 = fmaf(agg[f + 3], woL[(FIN + f + 3) * FOUT], a3);
        }
        float acc = (a0 + a1) + (a2 + a3);
        float e = __expf(2.f * acc);
        float r = __builtin_amdgcn_rcpf(e + 1.f);
        out[(size_t)qj * FOUT + lane] = fmaf(-2.f, r, 1.f);
    }
    WSYNC();
}

// ---------------- main: one wave per FOUR queries, fully scalarized --------------
__global__ __launch_bounds__(WPB * 64, 8) void gn_main(
    const float* __restrict__ x,
    const float* __restrict__ Wo, const float* __restrict__ bo,
    const float* __restrict__ coords4, const float* __restrict__ sqn,
    const float* __restrict__ feats,
    float* __restrict__ out)
{
    __shared__ unsigned short sel_s[WPB * QW * CAP];     // candidate indices
    __shared__ float fstage_s[WPB * KSEL * PPAD];
    __shared__ float agg_s[WPB * 48];

    const float INF = __builtin_inff();
    const int wv    = threadIdx.x >> 6;
    const int lane  = threadIdx.x & 63;
    const int qbase = (blockIdx.x * WPB + wv) * QW;      // 4 queries, same batch
    const int b     = qbase >> 12;
    const int n0    = qbase & (NN - 1);
    unsigned short* selp = sel_s + wv * QW * CAP;
    float* fstage = fstage_s + wv * (KSEL * PPAD);
    float* agg    = agg_s + wv * 48;

    const float4* c4  = ((const float4*)coords4) + (size_t)b * NN;
    const float*  sqb = sqn + (size_t)b * NN;

    // per-query constants -- individual scalars only
    float4 cq0 = c4[n0 + 0], cq1 = c4[n0 + 1], cq2 = c4[n0 + 2], cq3 = c4[n0 + 3];
    float sq0 = sqb[n0 + 0], sq1 = sqb[n0 + 1], sq2 = sqb[n0 + 2], sq3 = sqb[n0 + 3];

    // ---- pass 1: precomputed |cm|^2, per-query running min (self included) ----
    float km0 = INF, km1 = INF, km2 = INF, km3 = INF;
    #pragma unroll 4
    for (int i = 0; i < 64; ++i) {
        float4 cm = c4[i * 64 + lane];
        float s2  = sqb[i * 64 + lane];
        float dt0 = fmaf(cq0.x, cm.x, fmaf(cq0.y, cm.y, fmaf(cq0.z, cm.z, cq0.w * cm.w)));
        float dt1 = fmaf(cq1.x, cm.x, fmaf(cq1.y, cm.y, fmaf(cq1.z, cm.z, cq1.w * cm.w)));
        float dt2 = fmaf(cq2.x, cm.x, fmaf(cq2.y, cm.y, fmaf(cq2.z, cm.z, cq2.w * cm.w)));
        float dt3 = fmaf(cq3.x, cm.x, fmaf(cq3.y, cm.y, fmaf(cq3.z, cm.z, cq3.w * cm.w)));
        km0 = fminf(km0, fmaf(-2.f, dt0, s2 + sq0));
        km1 = fminf(km1, fmaf(-2.f, dt1, s2 + sq1));
        km2 = fminf(km2, fmaf(-2.f, dt2, s2 + sq2));
        km3 = fminf(km3, fmaf(-2.f, dt3, s2 + sq3));
    }
    unsigned kb0 = __float_as_uint(fmaxf(km0, 0.f));
    unsigned kb1 = __float_as_uint(fmaxf(km1, 0.f));
    unsigned kb2 = __float_as_uint(fmaxf(km2, 0.f));
    unsigned kb3 = __float_as_uint(fmaxf(km3, 0.f));

    // ---- bounds: 40th-smallest lane-min per query, TRUNCATED radix (bits 30..15)
    //      then widen low bits: UB' = p + 2^15 - 1 >= exact 40th value.
    //      Still an exact superset; only the candidate count grows (~0 extra).
    unsigned ub0 = 0, ub1 = 0, ub2 = 0, ub3 = 0;
    for (int bit = 30; bit >= 15; --bit) {
        unsigned msk = 1u << bit;
        unsigned t0 = ub0 | msk, t1 = ub1 | msk, t2 = ub2 | msk, t3 = ub3 | msk;
        if ((int)__popcll(__ballot(kb0 < t0)) < KSEL + 1) ub0 = t0;
        if ((int)__popcll(__ballot(kb1 < t1)) < KSEL + 1) ub1 = t1;
        if ((int)__popcll(__ballot(kb2 < t2)) < KSEL + 1) ub2 = t2;
        if ((int)__popcll(__ballot(kb3 < t3)) < KSEL + 1) ub3 = t3;
    }
    float UB0 = __uint_as_float(ub0 | 0x7FFFu);
    float UB1 = __uint_as_float(ub1 | 0x7FFFu);
    float UB2 = __uint_as_float(ub2 | 0x7FFFu);
    float UB3 = __uint_as_float(ub3 | 0x7FFFu);

    // ---- compact pass: ballot/prefix slot assignment (no LDS atomics) ----
    unsigned cc0 = 0, cc1 = 0, cc2 = 0, cc3 = 0;
    #pragma unroll 4
    for (int i = 0; i < 64; ++i) {
        int m = i * 64 + lane;
        float4 cm = c4[m];
        float s2  = sqb[m];
        float dt0 = fmaf(cq0.x, cm.x, fmaf(cq0.y, cm.y, fmaf(cq0.z, cm.z, cq0.w * cm.w)));
        float dt1 = fmaf(cq1.x, cm.x, fmaf(cq1.y, cm.y, fmaf(cq1.z, cm.z, cq1.w * cm.w)));
        float dt2 = fmaf(cq2.x, cm.x, fmaf(cq2.y, cm.y, fmaf(cq2.z, cm.z, cq2.w * cm.w)));
        float dt3 = fmaf(cq3.x, cm.x, fmaf(cq3.y, cm.y, fmaf(cq3.z, cm.z, cq3.w * cm.w)));
        float d0 = fmaf(-2.f, dt0, s2 + sq0);
        float d1 = fmaf(-2.f, dt1, s2 + sq1);
        float d2 = fmaf(-2.f, dt2, s2 + sq2);
        float d3 = fmaf(-2.f, dt3, s2 + sq3);
        bool t0 = (d0 <= UB0) && (m != n0 + 0);
        bool t1 = (d1 <= UB1) && (m != n0 + 1);
        bool t2 = (d2 <= UB2) && (m != n0 + 2);
        bool t3 = (d3 <= UB3) && (m != n0 + 3);
        unsigned long long b0 = __ballot(t0);
        unsigned long long b1 = __ballot(t1);
        unsigned long long b2 = __ballot(t2);
        unsigned long long b3 = __ballot(t3);
        if (t0) {
            unsigned s = cc0 + (unsigned)lane_prefix(b0);
            if (s < CAP) selp[0 * CAP + s] = (unsigned short)m;
        }
        if (t1) {
            unsigned s = cc1 + (unsigned)lane_prefix(b1);
            if (s < CAP) selp[1 * CAP + s] = (unsigned short)m;
        }
        if (t2) {
            unsigned s = cc2 + (unsigned)lane_prefix(b2);
            if (s < CAP) selp[2 * CAP + s] = (unsigned short)m;
        }
        if (t3) {
            unsigned s = cc3 + (unsigned)lane_prefix(b3);
            if (s < CAP) selp[3 * CAP + s] = (unsigned short)m;
        }
        cc0 += (unsigned)__popcll(b0);
        cc1 += (unsigned)__popcll(b1);
        cc2 += (unsigned)__popcll(b2);
        cc3 += (unsigned)__popcll(b3);
    }
    WSYNC();

    // ---- four explicit tail calls (no runtime-indexed private state) ----
    tail_query(lane, b, n0 + 0, qbase + 0, (int)cc0, selp + 0 * CAP,
               c4, sqb, feats, x, Wo, bo, fstage, agg, out);
    tail_query(lane, b, n0 + 1, qbase + 1, (int)cc1, selp + 1 * CAP,
               c4, sqb, feats, x, Wo, bo, fstage, agg, out);
    tail_query(lane, b, n0 + 2, qbase + 2, (int)cc2, selp + 2 * CAP,
               c4, sqb, feats, x, Wo, bo, fstage, agg, out);
    tail_query(lane, b, n0 + 3, qbase + 3, (int)cc3, selp + 3 * CAP,
               c4, sqb, feats, x, Wo, bo, fstage, agg, out);
}

extern "C" void kernel_launch(void* const* d_in, const int* in_sizes, int n_in,
                              void* d_out, int out_size, void* d_ws, size_t ws_size,
                              hipStream_t stream) {
    const float* x  = (const float*)d_in[0];
    const float* Wf = (const float*)d_in[1];
    const float* bf = (const float*)d_in[2];
    const float* Ws = (const float*)d_in[3];
    const float* bs = (const float*)d_in[4];
    const float* Wo = (const float*)d_in[5];
    const float* bo = (const float*)d_in[6];
    float* outp = (float*)d_out;

    float* ws      = (float*)d_ws;
    float* coords4 = ws;                      // 32768*4  = 131072 floats
    float* feats   = ws + 131072;             // 32768*24 = 786432 floats
    float* sqn     = ws + 131072 + 786432;    // 32768 floats

    gn_pre<<<(32768 * 4) / 256, 256, 0, stream>>>(x, Wf, bf, Ws, bs, coords4, feats, sqn);
    gn_main<<<32768 / (WPB * QW), WPB * 64, 0, stream>>>(x, Wo, bo, coords4, sqn, feats, outp);
}